// Round 2
// baseline (2082.338 us; speedup 1.0000x reference)
//
#include <hip/hip_runtime.h>

typedef float f32x4 __attribute__((ext_vector_type(4)));

#define EMBED 256

// ---------------- GEMM: proj[n][m] = sum_k x[n][k] * W[m][k] + b[m] ----------------
// Tile: BM=128 rows x BN=128 cols, BK=32. 256 threads, 8x8 micro-tile per thread.
// W-tile staged transposed in LDS [k][col] (pad +4 -> conflict-free reads/writes).
// A (x) streamed directly from global with broadcast float4 loads (L1-resident).
// No fp32-input MFMA on CDNA4 -> vector ALU GEMM (157.3 TF ceiling).
__global__ __launch_bounds__(256) void gemm_xwT(const float* __restrict__ A,
                                                const float* __restrict__ W,
                                                const float* __restrict__ bias,
                                                float* __restrict__ C,
                                                int M)
{
    __shared__ float Bt[32][132];
    const int tid = threadIdx.x;
    const int tx = tid & 15;        // 16 col-groups
    const int ty = tid >> 4;        // 16 row-groups
    const long row0 = (long)blockIdx.x * 128;
    const int col0 = blockIdx.y * 128;

    float acc[8][8];
#pragma unroll
    for (int r = 0; r < 8; ++r)
#pragma unroll
        for (int c = 0; c < 8; ++c) acc[r][c] = 0.f;

    // per-thread A row pointers (clamped at tail so loads stay in-bounds)
    const float* aptr[8];
#pragma unroll
    for (int r = 0; r < 8; ++r) {
        long row = row0 + ty * 8 + r;
        if (row > M - 1) row = M - 1;
        aptr[r] = A + row * (long)EMBED;
    }

    const int cs = tid & 127;   // staging col
    const int kq = tid >> 7;    // 0/1

    for (int kt = 0; kt < EMBED; kt += 32) {
        // stage W[(col0+c)][kt..kt+31] -> Bt[k][c]  (W is 256 KB -> L2-resident)
#pragma unroll
        for (int q = 0; q < 4; ++q) {
            const int k4 = kq + q * 2;  // covers 0..7
            f32x4 w = *(const f32x4*)(W + (long)(col0 + cs) * EMBED + kt + k4 * 4);
            Bt[k4 * 4 + 0][cs] = w.x;
            Bt[k4 * 4 + 1][cs] = w.y;
            Bt[k4 * 4 + 2][cs] = w.z;
            Bt[k4 * 4 + 3][cs] = w.w;
        }
        __syncthreads();

#pragma unroll
        for (int k4 = 0; k4 < 8; ++k4) {
            f32x4 av[8];
#pragma unroll
            for (int r = 0; r < 8; ++r)
                av[r] = *(const f32x4*)(aptr[r] + kt + k4 * 4);
#pragma unroll
            for (int j = 0; j < 4; ++j) {
                const f32x4 w0 = *(const f32x4*)&Bt[k4 * 4 + j][tx * 4];
                const f32x4 w1 = *(const f32x4*)&Bt[k4 * 4 + j][64 + tx * 4];
#pragma unroll
                for (int r = 0; r < 8; ++r) {
                    const float a = av[r][j];
                    acc[r][0] += a * w0.x;  acc[r][1] += a * w0.y;
                    acc[r][2] += a * w0.z;  acc[r][3] += a * w0.w;
                    acc[r][4] += a * w1.x;  acc[r][5] += a * w1.y;
                    acc[r][6] += a * w1.z;  acc[r][7] += a * w1.w;
                }
            }
        }
        __syncthreads();
    }

    // bias + store
    const f32x4 b0 = *(const f32x4*)(bias + col0 + tx * 4);
    const f32x4 b1 = *(const f32x4*)(bias + col0 + 64 + tx * 4);
#pragma unroll
    for (int r = 0; r < 8; ++r) {
        const long row = row0 + ty * 8 + r;
        if (row < M) {
            f32x4 o0 = { acc[r][0] + b0.x, acc[r][1] + b0.y, acc[r][2] + b0.z, acc[r][3] + b0.w };
            f32x4 o1 = { acc[r][4] + b1.x, acc[r][5] + b1.y, acc[r][6] + b1.z, acc[r][7] + b1.w };
            *(f32x4*)(C + row * (long)EMBED + col0 + tx * 4) = o0;
            *(f32x4*)(C + row * (long)EMBED + col0 + 64 + tx * 4) = o1;
        }
    }
}

// ---------------- Gather: out[e][:] = proj[index[e]][:] ----------------
// One wave (64 lanes) per edge: lane i moves one float4 -> 1 KB/row, fully
// coalesced on both sides. Index is int32 (JAX x64-disabled demotes int64).
// Non-temporal stores so the 1.6 GB output stream doesn't evict proj from L3.
__global__ __launch_bounds__(256) void gather_rows(const float* __restrict__ proj,
                                                   const int* __restrict__ idx,
                                                   float* __restrict__ out,
                                                   long E)
{
    const int lane = threadIdx.x & 63;
    const int w = threadIdx.x >> 6;
    const long e = (long)blockIdx.x * 4 + w;
    if (e < E) {
        const long node = (long)idx[e];
        f32x4 v = *(const f32x4*)(proj + node * (long)EMBED + lane * 4);
        f32x4* dst = (f32x4*)(out + e * (long)EMBED + lane * 4);
        __builtin_nontemporal_store(v, dst);
    }
}

extern "C" void kernel_launch(void* const* d_in, const int* in_sizes, int n_in,
                              void* d_out, int out_size, void* d_ws, size_t ws_size,
                              hipStream_t stream) {
    const float* x = (const float*)d_in[0];
    const int* index = (const int*)d_in[1];   // int32: JAX default (x64 off) demotes int64
    const float* W = (const float*)d_in[2];
    const float* b = (const float*)d_in[3];
    float* out = (float*)d_out;

    const int M = in_sizes[0] / EMBED;       // 100000 nodes
    const long E = (long)in_sizes[1];        // 1600000 edges

    float* proj = (float*)d_ws;              // needs M*256*4 = 102.4 MB of ws

    dim3 ggrid((M + 127) / 128, 2);
    gemm_xwT<<<ggrid, 256, 0, stream>>>(x, W, b, proj, M);

    const long nblk = (E + 3) / 4;
    gather_rows<<<(unsigned)nblk, 256, 0, stream>>>(proj, index, out, E);
}